// Round 6
// baseline (216.113 us; speedup 1.0000x reference)
//
#include <hip/hip_runtime.h>
#include <math.h>

// B=16, N=1024, C_IN=256, C_OUT=256, POOL_RATIO=0.5
#define Bsz 16
#define Nn  1024

// d_out layout (float32): x_out[16,1024,256], adj_out[16,1024,1024], new_mask[16,1024], new_n[16]
#define ADJ_OFF    (16*1024*256)
#define MASK_OFF   (ADJ_OFF + 16*1024*1024)
#define NN_OFF     (MASK_OFF + 16*1024)

typedef unsigned long long u64;
typedef unsigned short u16;
typedef short bf16x8 __attribute__((ext_vector_type(8)));
typedef float f32x4  __attribute__((ext_vector_type(4)));

static __device__ inline u16 f2bf(float f) {
    unsigned u = __float_as_uint(f);
    u += 0x7fffu + ((u >> 16) & 1u);
    return (u16)(u >> 16);
}

// spread 16 bits to every-4th position (bit q -> bit 4q)
static __device__ inline u64 spread4(u64 x) {
    x &= 0xFFFFULL;
    x = (x | (x << 24)) & 0x000000FF000000FFULL;
    x = (x | (x << 12)) & 0x000F000F000F000FULL;
    x = (x | (x << 6))  & 0x0303030303030303ULL;
    x = (x | (x << 3))  & 0x1111111111111111ULL;
    return x;
}

// expand 8 adjacency bits -> bf16x8 (bit -> 1.0bf16 = 0x3F80, exact same value as f2bf(1.0f))
static __device__ inline bf16x8 expand8(unsigned kb) {
    union { unsigned u[4]; bf16x8 v; } r;
    #pragma unroll
    for (int p = 0; p < 4; ++p) {
        unsigned lo = (kb >> (2 * p)) & 1u;
        unsigned hi = (kb >> (2 * p + 1)) & 1u;
        r.u[p] = (lo ? 0x3F80u : 0u) | (hi ? 0x3F800000u : 0u);
    }
    return r.v;
}

// =============== k1: x->bf16 + z = x.(W.pool) (blocks 0-255) | W^T bf16 (blocks 256-271) ===============
__global__ __launch_bounds__(256) void k1(const float* __restrict__ x,
                                          const float* __restrict__ W,
                                          const float* __restrict__ pool,
                                          u16* __restrict__ XB,
                                          u16* __restrict__ WT,
                                          float* __restrict__ Z) {
    int bid = blockIdx.x, t = threadIdx.x, lane = t & 63, wid = t >> 6;
    if (bid < 256) {
        __shared__ float sp[256];
        __shared__ float swp[256];
        sp[t] = pool[t];
        __syncthreads();
        float acc = 0.f;
        const float* wr = W + t * 256;
        for (int j = 0; j < 256; j += 4) {
            float4 w4 = *(const float4*)&wr[j];
            acc = fmaf(w4.x, sp[j], fmaf(w4.y, sp[j + 1],
                  fmaf(w4.z, sp[j + 2], fmaf(w4.w, sp[j + 3], acc))));
        }
        swp[t] = acc;
        __syncthreads();
        const float* w4p = &swp[lane * 4];
        float wx = w4p[0], wy = w4p[1], wz = w4p[2], ww = w4p[3];
        int base = bid * 64 + wid * 16;
        #pragma unroll 1
        for (int rb = 0; rb < 4; ++rb) {
            float4 v[4];
            #pragma unroll
            for (int k = 0; k < 4; ++k)
                v[k] = ((const float4*)(x + (size_t)(base + rb * 4 + k) * 256))[lane];
            #pragma unroll
            for (int k = 0; k < 4; ++k) {
                int row = base + rb * 4 + k;
                ushort4 o;
                o.x = f2bf(v[k].x); o.y = f2bf(v[k].y); o.z = f2bf(v[k].z); o.w = f2bf(v[k].w);
                ((ushort4*)(XB + (size_t)row * 256))[lane] = o;
                float a = fmaf(v[k].x, wx, fmaf(v[k].y, wy, fmaf(v[k].z, wz, v[k].w * ww)));
                for (int off = 32; off > 0; off >>= 1) a += __shfl_down(a, off, 64);
                if (lane == 0) Z[row] = a;
            }
        }
    } else {
        __shared__ float sT[64][65];
        int bt = bid - 256;
        int tr = (bt >> 2) * 64, tc = (bt & 3) * 64;
        #pragma unroll
        for (int p = 0; p < 4; ++p) {
            int r = p * 16 + (t >> 4), c = (t & 15) * 4;
            float4 w = *(const float4*)&W[(size_t)(tr + r) * 256 + tc + c];
            sT[r][c] = w.x; sT[r][c + 1] = w.y; sT[r][c + 2] = w.z; sT[r][c + 3] = w.w;
        }
        __syncthreads();
        #pragma unroll
        for (int p = 0; p < 2; ++p) {
            int nl = p * 32 + (t >> 3), kl = (t & 7) * 8;
            u16 tmp[8];
            #pragma unroll
            for (int j = 0; j < 8; ++j) tmp[j] = f2bf(sT[kl + j][nl]);
            *(int4*)&WT[(size_t)(tc + nl) * 256 + tr + kl] = *(const int4*)tmp;
        }
    }
}

// =============== k2: XWBT = (XB@WT^T)^T per batch (blocks 0-255) | adj->bitmask + y (blocks 256-1279) ===============
__global__ __launch_bounds__(256) void k2(const u16* __restrict__ XB,
                                          const u16* __restrict__ WT,
                                          const float* __restrict__ adj,
                                          const float* __restrict__ Z,
                                          u16* __restrict__ XWBT,
                                          u64* __restrict__ ABITS,
                                          float* __restrict__ Y) {
    int t = threadIdx.x, lane = t & 63, wid = t >> 6;
    if (blockIdx.x < 256) {
        __shared__ __align__(16) short smem[2 * 128 * 72];
        short (*sA)[72] = (short (*)[72])smem;
        short (*sB)[72] = (short (*)[72])(smem + 128 * 72);
        int idx = blockIdx.x;
        int b  = (idx & 7) + ((idx >> 7) << 3);    // batch pinned to XCD (idx & 7)
        int tl = (idx >> 3) & 15;                  // 16 tiles per batch
        int bm = (b << 3) + (tl >> 1);
        int bn = tl & 1;
        int wr = (wid >> 1) * 64, wc = (wid & 1) * 64;
        int fm = lane & 15, fq = lane >> 4;

        f32x4 acc[4][4];
        #pragma unroll
        for (int i = 0; i < 4; ++i)
            #pragma unroll
            for (int j = 0; j < 4; ++j)
                acc[i][j] = (f32x4){0.f, 0.f, 0.f, 0.f};

        int sr = t >> 1, half = (t & 1) * 32;
        const u16* gA = XB + ((size_t)(bm * 128 + sr)) * 256 + half;
        const u16* gB = WT + ((size_t)(bn * 128 + sr)) * 256 + half;

        for (int kt = 0; kt < 4; ++kt) {
            __syncthreads();
            #pragma unroll
            for (int q = 0; q < 4; ++q) {
                *(int4*)&sA[sr][half + q * 8] = *(const int4*)&gA[kt * 64 + q * 8];
                *(int4*)&sB[sr][half + q * 8] = *(const int4*)&gB[kt * 64 + q * 8];
            }
            __syncthreads();
            #pragma unroll
            for (int ks = 0; ks < 64; ks += 32) {
                bf16x8 af[4], bfv[4];
                #pragma unroll
                for (int i = 0; i < 4; ++i)
                    af[i] = *(const bf16x8*)&sA[wr + i * 16 + fm][ks + fq * 8];
                #pragma unroll
                for (int j = 0; j < 4; ++j)
                    bfv[j] = *(const bf16x8*)&sB[wc + j * 16 + fm][ks + fq * 8];
                __builtin_amdgcn_s_setprio(1);
                #pragma unroll
                for (int i = 0; i < 4; ++i)
                    #pragma unroll
                    for (int j = 0; j < 4; ++j)
                        acc[i][j] = __builtin_amdgcn_mfma_f32_16x16x32_bf16(af[i], bfv[j], acc[i][j], 0, 0, 0);
                __builtin_amdgcn_s_setprio(0);
            }
        }
        // Transposed store via LDS so global writes are coalesced 16B chunks
        __syncthreads();
        short (*sT)[136] = (short (*)[136])smem;
        #pragma unroll
        for (int i = 0; i < 4; ++i) {
            int m = wr + i * 16 + fq * 4;
            #pragma unroll
            for (int j = 0; j < 4; ++j) {
                int c = wc + j * 16 + fm;
                #pragma unroll
                for (int r = 0; r < 4; ++r)
                    sT[c][m + r] = (short)f2bf(acc[i][j][r]);
            }
        }
        __syncthreads();
        u16* dst = XWBT + (size_t)b * 262144 + (size_t)(bn * 128) * 1024 + (bm & 7) * 128;
        int cl = t >> 4, mo = (t & 15) * 8;
        #pragma unroll
        for (int p = 0; p < 8; ++p) {
            int c = p * 16 + cl;
            *(int4*)&dst[(size_t)c * 1024 + mo] = *(const int4*)&sT[c][mo];
        }
    } else {
        int g = blockIdx.x - 256;
        int b = (g & 7) + ((g >> 9) << 3);
        int grp = (g >> 3) & 63;
        __shared__ float sZ[1024];
        ((float4*)sZ)[t] = ((const float4*)(Z + (b << 10)))[t];
        __syncthreads();
        const float* z0 = &sZ[lane * 4];
        #pragma unroll 1
        for (int rr = 0; rr < 4; ++rr) {
            int row = (b << 10) + grp * 16 + wid * 4 + rr;
            const float4* ar = (const float4*)(adj + (size_t)row * 1024);
            float4 v0 = ar[lane], v1 = ar[64 + lane], v2 = ar[128 + lane], v3 = ar[192 + lane];
            // ---- pack row into 1024-bit mask (canonical order: word w covers cols 64w..64w+63) ----
            u64 B00 = __ballot(v0.x != 0.f), B01 = __ballot(v0.y != 0.f);
            u64 B02 = __ballot(v0.z != 0.f), B03 = __ballot(v0.w != 0.f);
            u64 B10 = __ballot(v1.x != 0.f), B11 = __ballot(v1.y != 0.f);
            u64 B12 = __ballot(v1.z != 0.f), B13 = __ballot(v1.w != 0.f);
            u64 B20 = __ballot(v2.x != 0.f), B21 = __ballot(v2.y != 0.f);
            u64 B22 = __ballot(v2.z != 0.f), B23 = __ballot(v2.w != 0.f);
            u64 B30 = __ballot(v3.x != 0.f), B31 = __ballot(v3.y != 0.f);
            u64 B32 = __ballot(v3.z != 0.f), B33 = __ballot(v3.w != 0.f);
            u64 t0, t1, t2, t3;
            int c = (lane >> 2) & 3;
            if (c == 0)      { t0 = B00; t1 = B01; t2 = B02; t3 = B03; }
            else if (c == 1) { t0 = B10; t1 = B11; t2 = B12; t3 = B13; }
            else if (c == 2) { t0 = B20; t1 = B21; t2 = B22; t3 = B23; }
            else             { t0 = B30; t1 = B31; t2 = B32; t3 = B33; }
            int sh = (lane & 3) * 16;
            u64 wbits = spread4(t0 >> sh) | (spread4(t1 >> sh) << 1)
                      | (spread4(t2 >> sh) << 2) | (spread4(t3 >> sh) << 3);
            if (lane < 16) ABITS[(size_t)row * 16 + lane] = wbits;
            // ---- y = adj-row . z ----
            float a = v0.x * z0[0] + v0.y * z0[1] + v0.z * z0[2] + v0.w * z0[3];
            a += v1.x * z0[256] + v1.y * z0[257] + v1.z * z0[258] + v1.w * z0[259];
            a += v2.x * z0[512] + v2.y * z0[513] + v2.z * z0[514] + v2.w * z0[515];
            a += v3.x * z0[768] + v3.y * z0[769] + v3.z * z0[770] + v3.w * z0[771];
            for (int off = 32; off > 0; off >>= 1) a += __shfl_down(a, off, 64);
            if (lane == 0) Y[row] = a;
        }
    }
}

// =============== k4: fused {per-block redundant sort + pooling} + H-GEMM + XO (blocks 0-255) | AO (256-1279) ===============
// The k3 sort kernel is eliminated: keys (Y<<32)|idx are unique, so any correct sort
// gives the identical permutation -> each block sorts its own batch's 1024 keys in LDS
// (256-thread bitonic, 4 elems/thread) and derives nm/scale locally. One designated
// block per batch writes NM/new_n.
__global__ __launch_bounds__(256) void k4(const u64* __restrict__ ABITS,
                                          const u16* __restrict__ XWBT,
                                          const float* __restrict__ Y,
                                          const int* __restrict__ maskIn,
                                          const int* __restrict__ nNodes,
                                          const float* __restrict__ bias,
                                          const float* __restrict__ pool,
                                          float* __restrict__ NM,
                                          float* __restrict__ newN,
                                          float* __restrict__ XO,
                                          float* __restrict__ AO) {
    // LDS: region A [0,18432) = sBitsA (GEMM) / sRB (AO).  region B [18432,36864) =
    // sort scratch {sk 8K, nmLoc 4K}, later overlaid by sB (GEMM kt loop).
    __shared__ __align__(16) unsigned char smem[36864];
    __shared__ float sScale[128];
    __shared__ int   wsum[4];
    __shared__ float redb[4], redq[4];

    u64 (*sBitsA)[18] = (u64 (*)[18])smem;
    short (*sB)[72]   = (short (*)[72])(smem + 18432);
    u64*  sk    = (u64*)(smem + 18432);
    int*  nmLoc = (int*)(smem + 18432 + 8192);
    u64 (*sRB)[17] = (u64 (*)[17])smem;

    int t = threadIdx.x, lane = t & 63, wid = t >> 6;
    bool isGemm = blockIdx.x < 256;
    int b, tl = 0, bmt = 0, bn = 0, grp = 0;
    if (isGemm) {
        int idx = blockIdx.x;
        b = (idx & 7) + ((idx >> 7) << 3);         // batch pinned to XCD
        tl = (idx >> 3) & 15; bmt = tl >> 1; bn = tl & 1;
    } else {
        int g = blockIdx.x - 256;
        b = (g & 7) + ((g >> 9) << 3);
        grp = (g >> 3) & 63;
    }
    int base = b << 10;

    // ---- phase 0: pool/bias reductions, key load, region-A staging ----
    {
        float pv = pool[t];
        float bv = bias[t] * pv;
        float qv = pv * pv;
        for (int off = 32; off > 0; off >>= 1) {
            bv += __shfl_down(bv, off, 64);
            qv += __shfl_down(qv, off, 64);
        }
        if (lane == 0) { redb[wid] = bv; redq[wid] = qv; }
    }
    #pragma unroll
    for (int p = 0; p < 4; ++p) {
        int i = p * 256 + t;
        unsigned u = __float_as_uint(Y[base + i]);
        u = (u & 0x80000000u) ? ~u : (u | 0x80000000u);
        sk[i] = ((u64)u << 32) | (unsigned)i;
    }
    if (isGemm) {
        int r = t >> 1, hq = (t & 1) * 8;
        const u64* src = ABITS + ((size_t)(b * 1024 + bmt * 128 + r)) * 16 + hq;
        #pragma unroll
        for (int q = 0; q < 8; q += 2) {
            ulonglong2 v = *(const ulonglong2*)&src[q];
            sBitsA[r][hq + q] = v.x;
            sBitsA[r][hq + q + 1] = v.y;
        }
    } else {
        sRB[t >> 4][t & 15] = ABITS[((size_t)(base + grp * 16 + (t >> 4))) * 16 + (t & 15)];
    }
    __syncthreads();
    float sBP  = redb[0] + redb[1] + redb[2] + redb[3];
    float sINV = 1.0f / sqrtf(redq[0] + redq[1] + redq[2] + redq[3]);

    // ---- phase 1: bitonic sort of 1024 keys, 2 pairs/thread/stage ----
    for (int k = 2; k <= 1024; k <<= 1) {
        for (int j = k >> 1; j >= 1; j >>= 1) {
            #pragma unroll
            for (int p = 0; p < 2; ++p) {
                int q = p * 256 + t;                         // pair id 0..511
                int i = ((q & ~(j - 1)) << 1) | (q & (j - 1));
                int ip = i | j;
                bool up = ((i & k) == 0);
                u64 a = sk[i], c = sk[ip];
                if ((a > c) == up) { sk[i] = c; sk[ip] = a; }
            }
            __syncthreads();
        }
    }

    // ---- phase 2: rank among masked (thread owns positions 4t..4t+3) ----
    {
        int m[4], id4[4], ts = 0;
        #pragma unroll
        for (int s = 0; s < 4; ++s) {
            u64 v = sk[4 * t + s];
            int id = (int)(v & 1023u);
            id4[s] = id;
            int mm = maskIn[base + id];
            m[s] = mm; ts += mm;
        }
        int sc = ts;
        for (int off = 1; off < 64; off <<= 1) {
            int nv = __shfl_up(sc, off, 64);
            if (lane >= off) sc += nv;
        }
        if (lane == 63) wsum[wid] = sc;
        __syncthreads();
        int offset = 0;
        for (int w = 0; w < wid; ++w) offset += wsum[w];
        int run = sc - ts + offset;                          // exclusive rank
        int nn = nNodes[b];
        int nrem = (int)((float)nn * 0.5f);
        #pragma unroll
        for (int s = 0; s < 4; ++s) {
            int nm = (m[s] == 1 && run < nrem) ? 0 : m[s];
            run += m[s];
            nmLoc[id4[s]] = nm;
        }
        __syncthreads();

        if (isGemm) {
            if (t < 128) {
                int node = bmt * 128 + t;
                int nm = nmLoc[node];
                float yv = Y[base + node];
                sScale[t] = nm ? tanhf((yv + sBP) * sINV) : 0.0f;
            }
            if (tl == 0) {                                   // designated writer per batch
                #pragma unroll
                for (int p = 0; p < 4; ++p) {
                    int node = p * 256 + t;
                    NM[base + node] = (float)nmLoc[node];
                }
                if (t == 0) newN[b] = (float)(nn - nrem);
            }
        }
    }

    if (isGemm) {
        int wr = (wid >> 1) * 64, wc = (wid & 1) * 64;
        int fm = lane & 15, fq = lane >> 4;

        f32x4 acc[4][4];
        #pragma unroll
        for (int i = 0; i < 4; ++i)
            #pragma unroll
            for (int j = 0; j < 4; ++j)
                acc[i][j] = (f32x4){0.f, 0.f, 0.f, 0.f};

        int sr = t >> 1, half = (t & 1) * 32;
        const u16* gB = XWBT + (size_t)b * 262144 + (size_t)(bn * 128 + sr) * 1024 + half;

        for (int kt = 0; kt < 16; ++kt) {
            __syncthreads();                                 // sB region free (sort done / prev kt read)
            #pragma unroll
            for (int q = 0; q < 4; ++q)
                *(int4*)&sB[sr][half + q * 8] = *(const int4*)&gB[kt * 64 + q * 8];
            __syncthreads();
            u64 rb[4];
            #pragma unroll
            for (int i = 0; i < 4; ++i)
                rb[i] = sBitsA[wr + i * 16 + fm][kt];
            #pragma unroll
            for (int ks = 0; ks < 64; ks += 32) {
                bf16x8 af[4], bfv[4];
                #pragma unroll
                for (int i = 0; i < 4; ++i)
                    af[i] = expand8((unsigned)(rb[i] >> (ks + fq * 8)) & 0xFFu);
                #pragma unroll
                for (int j = 0; j < 4; ++j)
                    bfv[j] = *(const bf16x8*)&sB[wc + j * 16 + fm][ks + fq * 8];
                __builtin_amdgcn_s_setprio(1);
                #pragma unroll
                for (int i = 0; i < 4; ++i)
                    #pragma unroll
                    for (int j = 0; j < 4; ++j)
                        acc[i][j] = __builtin_amdgcn_mfma_f32_16x16x32_bf16(af[i], bfv[j], acc[i][j], 0, 0, 0);
                __builtin_amdgcn_s_setprio(0);
            }
        }
        float bj[4];
        #pragma unroll
        for (int j = 0; j < 4; ++j) bj[j] = bias[bn * 128 + wc + j * 16 + fm];
        int mb = base + bmt * 128 + wr;
        #pragma unroll
        for (int i = 0; i < 4; ++i) {
            int lrow = wr + i * 16 + fq * 4;
            int m0 = mb + i * 16 + fq * 4;
            float s0 = sScale[lrow], s1 = sScale[lrow + 1], s2 = sScale[lrow + 2], s3 = sScale[lrow + 3];
            #pragma unroll
            for (int j = 0; j < 4; ++j) {
                int c = bn * 128 + wc + j * 16 + fm;
                float* xo = XO + (size_t)m0 * 256 + c;
                xo[0]   = (acc[i][j][0] + bj[j]) * s0;
                xo[256] = (acc[i][j][1] + bj[j]) * s1;
                xo[512] = (acc[i][j][2] + bj[j]) * s2;
                xo[768] = (acc[i][j][3] + bj[j]) * s3;
            }
        }
    } else {
        int c0 = t * 4;
        float m0 = nmLoc[c0]     ? 1.f : 0.f;
        float m1 = nmLoc[c0 + 1] ? 1.f : 0.f;
        float m2 = nmLoc[c0 + 2] ? 1.f : 0.f;
        float m3 = nmLoc[c0 + 3] ? 1.f : 0.f;
        #pragma unroll 1
        for (int r = 0; r < 16; ++r) {
            int rloc = grp * 16 + r;
            int nmRow = nmLoc[rloc];
            float4* aor = (float4*)(AO + (size_t)(base + rloc) * 1024);
            if (nmRow) {
                unsigned rbits = (unsigned)(sRB[r][t >> 4] >> (4 * (t & 15))) & 0xFu;
                float4 o;
                o.x = (rbits & 1u) ? m0 : 0.f;
                o.y = (rbits & 2u) ? m1 : 0.f;
                o.z = (rbits & 4u) ? m2 : 0.f;
                o.w = (rbits & 8u) ? m3 : 0.f;
                aor[t] = o;
            } else {
                aor[t] = make_float4(0.f, 0.f, 0.f, 0.f);
            }
        }
    }
}

extern "C" void kernel_launch(void* const* d_in, const int* in_sizes, int n_in,
                              void* d_out, int out_size, void* d_ws, size_t ws_size,
                              hipStream_t stream) {
    const float* x      = (const float*)d_in[0];
    const float* adj    = (const float*)d_in[1];
    const int*   mask   = (const int*)d_in[2];
    const int*   nnodes = (const int*)d_in[3];
    const float* W      = (const float*)d_in[4];
    const float* bias   = (const float*)d_in[5];
    const float* pool   = (const float*)d_in[6];

    float* out = (float*)d_out;
    float* XO  = out;
    float* AO  = out + ADJ_OFF;
    float* NM  = out + MASK_OFF;
    float* NNo = out + NN_OFF;

    char* w = (char*)d_ws;
    u16*   XB     = (u16*)(w);                    //  8,388,608 B
    u16*   WT     = (u16*)(w + 8388608);          //    131,072
    u16*   XWBT   = (u16*)(w + 8519680);          //  8,388,608
    u64*   ABITS  = (u64*)(w + 16908288);         //  2,097,152
    float* Z      = (float*)(w + 19005440);       //     65,536
    float* Y      = (float*)(w + 19070976);       //     65,536

    k1<<<272, 256, 0, stream>>>(x, W, pool, XB, WT, Z);
    k2<<<1280, 256, 0, stream>>>(XB, WT, adj, Z, XWBT, ABITS, Y);
    k4<<<1280, 256, 0, stream>>>(ABITS, XWBT, Y, mask, nnodes, bias, pool, NM, NNo, XO, AO);
}

// Round 7
// 203.362 us; speedup vs baseline: 1.0627x; 1.0627x over previous
//
#include <hip/hip_runtime.h>
#include <math.h>

// B=16, N=1024, C_IN=256, C_OUT=256, POOL_RATIO=0.5
#define Bsz 16
#define Nn  1024

// d_out layout (float32): x_out[16,1024,256], adj_out[16,1024,1024], new_mask[16,1024], new_n[16]
#define ADJ_OFF    (16*1024*256)
#define MASK_OFF   (ADJ_OFF + 16*1024*1024)
#define NN_OFF     (MASK_OFF + 16*1024)

typedef unsigned long long u64;
typedef unsigned short u16;
typedef short bf16x8 __attribute__((ext_vector_type(8)));
typedef float f32x4  __attribute__((ext_vector_type(4)));

static __device__ inline u16 f2bf(float f) {
    unsigned u = __float_as_uint(f);
    u += 0x7fffu + ((u >> 16) & 1u);
    return (u16)(u >> 16);
}

// spread 16 bits to every-4th position (bit q -> bit 4q)
static __device__ inline u64 spread4(u64 x) {
    x &= 0xFFFFULL;
    x = (x | (x << 24)) & 0x000000FF000000FFULL;
    x = (x | (x << 12)) & 0x000F000F000F000FULL;
    x = (x | (x << 6))  & 0x0303030303030303ULL;
    x = (x | (x << 3))  & 0x1111111111111111ULL;
    return x;
}

// expand 8 adjacency bits -> bf16x8 (bit -> 1.0bf16 = 0x3F80, exact same value as f2bf(1.0f))
static __device__ inline bf16x8 expand8(unsigned kb) {
    union { unsigned u[4]; bf16x8 v; } r;
    #pragma unroll
    for (int p = 0; p < 4; ++p) {
        unsigned lo = (kb >> (2 * p)) & 1u;
        unsigned hi = (kb >> (2 * p + 1)) & 1u;
        r.u[p] = (lo ? 0x3F80u : 0u) | (hi ? 0x3F800000u : 0u);
    }
    return r.v;
}

// =============== k1: x->bf16 + z = x.(W.pool) (blocks 0-255) | W^T bf16 (blocks 256-271) ===============
__global__ __launch_bounds__(256) void k1(const float* __restrict__ x,
                                          const float* __restrict__ W,
                                          const float* __restrict__ pool,
                                          u16* __restrict__ XB,
                                          u16* __restrict__ WT,
                                          float* __restrict__ Z) {
    int bid = blockIdx.x, t = threadIdx.x, lane = t & 63, wid = t >> 6;
    if (bid < 256) {
        __shared__ float sp[256];
        __shared__ float swp[256];
        sp[t] = pool[t];
        __syncthreads();
        float acc = 0.f;
        const float* wr = W + t * 256;
        for (int j = 0; j < 256; j += 4) {
            float4 w4 = *(const float4*)&wr[j];
            acc = fmaf(w4.x, sp[j], fmaf(w4.y, sp[j + 1],
                  fmaf(w4.z, sp[j + 2], fmaf(w4.w, sp[j + 3], acc))));
        }
        swp[t] = acc;
        __syncthreads();
        const float* w4p = &swp[lane * 4];
        float wx = w4p[0], wy = w4p[1], wz = w4p[2], ww = w4p[3];
        int base = bid * 64 + wid * 16;
        #pragma unroll 1
        for (int rb = 0; rb < 4; ++rb) {
            float4 v[4];
            #pragma unroll
            for (int k = 0; k < 4; ++k)
                v[k] = ((const float4*)(x + (size_t)(base + rb * 4 + k) * 256))[lane];
            #pragma unroll
            for (int k = 0; k < 4; ++k) {
                int row = base + rb * 4 + k;
                ushort4 o;
                o.x = f2bf(v[k].x); o.y = f2bf(v[k].y); o.z = f2bf(v[k].z); o.w = f2bf(v[k].w);
                ((ushort4*)(XB + (size_t)row * 256))[lane] = o;
                float a = fmaf(v[k].x, wx, fmaf(v[k].y, wy, fmaf(v[k].z, wz, v[k].w * ww)));
                for (int off = 32; off > 0; off >>= 1) a += __shfl_down(a, off, 64);
                if (lane == 0) Z[row] = a;
            }
        }
    } else {
        __shared__ float sT[64][65];
        int bt = bid - 256;
        int tr = (bt >> 2) * 64, tc = (bt & 3) * 64;
        #pragma unroll
        for (int p = 0; p < 4; ++p) {
            int r = p * 16 + (t >> 4), c = (t & 15) * 4;
            float4 w = *(const float4*)&W[(size_t)(tr + r) * 256 + tc + c];
            sT[r][c] = w.x; sT[r][c + 1] = w.y; sT[r][c + 2] = w.z; sT[r][c + 3] = w.w;
        }
        __syncthreads();
        #pragma unroll
        for (int p = 0; p < 2; ++p) {
            int nl = p * 32 + (t >> 3), kl = (t & 7) * 8;
            u16 tmp[8];
            #pragma unroll
            for (int j = 0; j < 8; ++j) tmp[j] = f2bf(sT[kl + j][nl]);
            *(int4*)&WT[(size_t)(tc + nl) * 256 + tr + kl] = *(const int4*)tmp;
        }
    }
}

// =============== k2: XWBT = (XB@WT^T)^T per batch (blocks 0-255, barrier-free direct-load GEMM)
//                 | adj->bitmask + y (blocks 256-1279) ===============
// XB (512KB/batch, XCD-pinned) and WT (128KB) are L2-resident: LDS staging of them was
// pure overhead (2 barriers + vmcnt(0) drain per kt). Read MFMA fragments directly.
__global__ __launch_bounds__(256) void k2(const u16* __restrict__ XB,
                                          const u16* __restrict__ WT,
                                          const float* __restrict__ adj,
                                          const float* __restrict__ Z,
                                          u16* __restrict__ XWBT,
                                          u64* __restrict__ ABITS,
                                          float* __restrict__ Y) {
    int t = threadIdx.x, lane = t & 63, wid = t >> 6;
    if (blockIdx.x < 256) {
        __shared__ __align__(16) short sT[128][136];
        int idx = blockIdx.x;
        int b  = (idx & 7) + ((idx >> 7) << 3);    // batch pinned to XCD (idx & 7)
        int tl = (idx >> 3) & 15;                  // 16 tiles per batch
        int bm = (b << 3) + (tl >> 1);
        int bn = tl & 1;
        int wr = (wid >> 1) * 64, wc = (wid & 1) * 64;
        int fm = lane & 15, fq = lane >> 4;

        f32x4 acc[4][4];
        #pragma unroll
        for (int i = 0; i < 4; ++i)
            #pragma unroll
            for (int j = 0; j < 4; ++j)
                acc[i][j] = (f32x4){0.f, 0.f, 0.f, 0.f};

        const u16* baseA = XB + ((size_t)(bm * 128)) * 256;
        const u16* baseB = WT + ((size_t)(bn * 128)) * 256;

        #pragma unroll 1
        for (int kt = 0; kt < 4; ++kt) {
            #pragma unroll
            for (int ks = 0; ks < 64; ks += 32) {
                int ko = kt * 64 + ks + fq * 8;
                bf16x8 af[4], bfv[4];
                #pragma unroll
                for (int i = 0; i < 4; ++i)
                    af[i] = *(const bf16x8*)&baseA[(size_t)(wr + i * 16 + fm) * 256 + ko];
                #pragma unroll
                for (int j = 0; j < 4; ++j)
                    bfv[j] = *(const bf16x8*)&baseB[(size_t)(wc + j * 16 + fm) * 256 + ko];
                __builtin_amdgcn_s_setprio(1);
                #pragma unroll
                for (int i = 0; i < 4; ++i)
                    #pragma unroll
                    for (int j = 0; j < 4; ++j)
                        acc[i][j] = __builtin_amdgcn_mfma_f32_16x16x32_bf16(af[i], bfv[j], acc[i][j], 0, 0, 0);
                __builtin_amdgcn_s_setprio(0);
            }
        }
        // Transposed store via LDS so global writes are coalesced 16B chunks
        #pragma unroll
        for (int i = 0; i < 4; ++i) {
            int m = wr + i * 16 + fq * 4;
            #pragma unroll
            for (int j = 0; j < 4; ++j) {
                int c = wc + j * 16 + fm;
                #pragma unroll
                for (int r = 0; r < 4; ++r)
                    sT[c][m + r] = (short)f2bf(acc[i][j][r]);
            }
        }
        __syncthreads();
        u16* dst = XWBT + (size_t)b * 262144 + (size_t)(bn * 128) * 1024 + (bm & 7) * 128;
        int cl = t >> 4, mo = (t & 15) * 8;
        #pragma unroll
        for (int p = 0; p < 8; ++p) {
            int c = p * 16 + cl;
            *(int4*)&dst[(size_t)c * 1024 + mo] = *(const int4*)&sT[c][mo];
        }
    } else {
        int g = blockIdx.x - 256;
        int b = (g & 7) + ((g >> 9) << 3);
        int grp = (g >> 3) & 63;
        __shared__ float sZ[1024];
        ((float4*)sZ)[t] = ((const float4*)(Z + (b << 10)))[t];
        __syncthreads();
        const float* z0 = &sZ[lane * 4];
        #pragma unroll 1
        for (int rr = 0; rr < 4; ++rr) {
            int row = (b << 10) + grp * 16 + wid * 4 + rr;
            const float4* ar = (const float4*)(adj + (size_t)row * 1024);
            float4 v0 = ar[lane], v1 = ar[64 + lane], v2 = ar[128 + lane], v3 = ar[192 + lane];
            // ---- pack row into 1024-bit mask (canonical order: word w covers cols 64w..64w+63) ----
            u64 B00 = __ballot(v0.x != 0.f), B01 = __ballot(v0.y != 0.f);
            u64 B02 = __ballot(v0.z != 0.f), B03 = __ballot(v0.w != 0.f);
            u64 B10 = __ballot(v1.x != 0.f), B11 = __ballot(v1.y != 0.f);
            u64 B12 = __ballot(v1.z != 0.f), B13 = __ballot(v1.w != 0.f);
            u64 B20 = __ballot(v2.x != 0.f), B21 = __ballot(v2.y != 0.f);
            u64 B22 = __ballot(v2.z != 0.f), B23 = __ballot(v2.w != 0.f);
            u64 B30 = __ballot(v3.x != 0.f), B31 = __ballot(v3.y != 0.f);
            u64 B32 = __ballot(v3.z != 0.f), B33 = __ballot(v3.w != 0.f);
            u64 t0, t1, t2, t3;
            int c = (lane >> 2) & 3;
            if (c == 0)      { t0 = B00; t1 = B01; t2 = B02; t3 = B03; }
            else if (c == 1) { t0 = B10; t1 = B11; t2 = B12; t3 = B13; }
            else if (c == 2) { t0 = B20; t1 = B21; t2 = B22; t3 = B23; }
            else             { t0 = B30; t1 = B31; t2 = B32; t3 = B33; }
            int sh = (lane & 3) * 16;
            u64 wbits = spread4(t0 >> sh) | (spread4(t1 >> sh) << 1)
                      | (spread4(t2 >> sh) << 2) | (spread4(t3 >> sh) << 3);
            if (lane < 16) ABITS[(size_t)row * 16 + lane] = wbits;
            // ---- y = adj-row . z ----
            float a = v0.x * z0[0] + v0.y * z0[1] + v0.z * z0[2] + v0.w * z0[3];
            a += v1.x * z0[256] + v1.y * z0[257] + v1.z * z0[258] + v1.w * z0[259];
            a += v2.x * z0[512] + v2.y * z0[513] + v2.z * z0[514] + v2.w * z0[515];
            a += v3.x * z0[768] + v3.y * z0[769] + v3.z * z0[770] + v3.w * z0[771];
            for (int off = 32; off > 0; off >>= 1) a += __shfl_down(a, off, 64);
            if (lane == 0) Y[row] = a;
        }
    }
}

// =============== k3: per-batch stable ascending argsort + mask pooling (bitonic, measured-best) ===============
__device__ inline u64 shfl_xor_u64(u64 v, int m) {
    int lo = __shfl_xor((int)(v & 0xffffffffULL), m, 64);
    int hi = __shfl_xor((int)(v >> 32), m, 64);
    return ((u64)(unsigned)hi << 32) | (unsigned)lo;
}

__global__ __launch_bounds__(1024) void k3(const float* __restrict__ Y,
                                           const int* __restrict__ maskIn,
                                           const int* __restrict__ nNodes,
                                           const float* __restrict__ bias,
                                           const float* __restrict__ pool,
                                           float* __restrict__ SCALE,
                                           float* __restrict__ NM,
                                           float* __restrict__ newN,
                                           u64* __restrict__ NMBITS) {
    __shared__ u64 s[1024];
    __shared__ int wsum[16];
    __shared__ int nmLoc[1024];
    __shared__ float redb[4], redq[4];
    __shared__ float sBP, sINV;

    int b = blockIdx.x, t = threadIdx.x, lane = t & 63, wid = t >> 6;
    int base = b << 10;

    if (t < 256) {
        float pv = pool[t];
        float bv = bias[t] * pv;
        float qv = pv * pv;
        for (int off = 32; off > 0; off >>= 1) {
            bv += __shfl_down(bv, off, 64);
            qv += __shfl_down(qv, off, 64);
        }
        if (lane == 0) { redb[wid] = bv; redq[wid] = qv; }
    }
    __syncthreads();
    if (t == 0) {
        sBP  = redb[0] + redb[1] + redb[2] + redb[3];
        sINV = 1.0f / sqrtf(redq[0] + redq[1] + redq[2] + redq[3]);
    }

    float ky = Y[base + t];
    unsigned u = __float_as_uint(ky);
    u = (u & 0x80000000u) ? ~u : (u | 0x80000000u);
    u64 val = ((u64)u << 32) | (unsigned)t;

    for (int k = 2; k <= 1024; k <<= 1) {
        bool up = ((t & k) == 0);
        int j = k >> 1;
        for (; j >= 64; j >>= 1) {
            s[t] = val; __syncthreads();
            u64 p = s[t ^ j]; __syncthreads();
            bool keepMin = (up == ((t & j) == 0));
            bool pLess = p < val;
            val = (keepMin == pLess) ? p : val;
        }
        for (; j >= 1; j >>= 1) {
            u64 p = shfl_xor_u64(val, j);
            bool keepMin = (up == ((t & j) == 0));
            bool pLess = p < val;
            val = (keepMin == pLess) ? p : val;
        }
    }

    int idx = (int)(val & 1023u);
    int mval = maskIn[base + idx];
    int sc = mval;
    for (int off = 1; off < 64; off <<= 1) {
        int nv = __shfl_up(sc, off, 64);
        if (lane >= off) sc += nv;
    }
    if (lane == 63) wsum[wid] = sc;
    __syncthreads();
    int offset = 0;
    for (int w = 0; w < wid; ++w) offset += wsum[w];
    int rank = sc + offset - mval;
    int nn = nNodes[b];
    int nrem = (int)((float)nn * 0.5f);
    int nm = (mval == 1 && rank < nrem) ? 0 : mval;
    nmLoc[idx] = nm;
    NM[base + idx] = (float)nm;
    if (t == 0) newN[b] = (float)(nn - nrem);
    __syncthreads();

    int myNm = nmLoc[t];
    u64 bmask = __ballot(myNm != 0);
    if (lane == 0) NMBITS[b * 16 + wid] = bmask;
    float yr = Y[base + t];
    SCALE[base + t] = myNm ? tanhf((yr + sBP) * sINV) : 0.0f;
}

// =============== k4: H=Abits@XWBT^T + x_out epilogue (blocks 0-255, barrier-free direct-load GEMM)
//                 | AO dense write (blocks 256-1279) ===============
// XWBT (512KB/batch) is XCD-L2-resident (FETCH_SIZE ~5.5MB confirms): LDS staging of it
// cost 32 barriers + 16 vmcnt(0) drains per block and held the kernel at 21% BW / 5.8%
// MfmaUtil. Only the tiny bit panel stays in LDS (staged once).
__global__ __launch_bounds__(256) void k4(const u64* __restrict__ ABITS,
                                          const u16* __restrict__ XWBT,
                                          const float* __restrict__ SCALE,
                                          const float* __restrict__ bias,
                                          const u64* __restrict__ NMBITS,
                                          float* __restrict__ XO,
                                          float* __restrict__ AO) {
    int t = threadIdx.x, lane = t & 63, wid = t >> 6;
    if (blockIdx.x < 256) {
        __shared__ u64 sBitsA[128][18];   // 18,432 B, staged once
        int idx = blockIdx.x;
        int b   = (idx & 7) + ((idx >> 7) << 3);   // batch pinned to XCD (idx & 7)
        int tl  = (idx >> 3) & 15;
        int bmt = tl >> 1, bn = tl & 1;
        int wr = (wid >> 1) * 64, wc = (wid & 1) * 64;
        int fm = lane & 15, fq = lane >> 4;

        {
            int r = t >> 1, hq = (t & 1) * 8;
            const u64* src = ABITS + ((size_t)(b * 1024 + bmt * 128 + r)) * 16 + hq;
            #pragma unroll
            for (int q = 0; q < 8; q += 2) {
                ulonglong2 v = *(const ulonglong2*)&src[q];
                sBitsA[r][hq + q] = v.x;
                sBitsA[r][hq + q + 1] = v.y;
            }
        }

        f32x4 acc[4][4];
        #pragma unroll
        for (int i = 0; i < 4; ++i)
            #pragma unroll
            for (int j = 0; j < 4; ++j)
                acc[i][j] = (f32x4){0.f, 0.f, 0.f, 0.f};

        const u16* baseB = XWBT + (size_t)b * 262144 + (size_t)(bn * 128) * 1024;
        __syncthreads();   // sBitsA ready; no further barriers

        #pragma unroll 1
        for (int kt = 0; kt < 16; ++kt) {
            u64 rb[4];
            #pragma unroll
            for (int i = 0; i < 4; ++i)
                rb[i] = sBitsA[wr + i * 16 + fm][kt];
            #pragma unroll
            for (int ks = 0; ks < 64; ks += 32) {
                bf16x8 af[4], bfv[4];
                #pragma unroll
                for (int j = 0; j < 4; ++j)
                    bfv[j] = *(const bf16x8*)&baseB[(size_t)(wc + j * 16 + fm) * 1024 + kt * 64 + ks + fq * 8];
                #pragma unroll
                for (int i = 0; i < 4; ++i)
                    af[i] = expand8((unsigned)(rb[i] >> (ks + fq * 8)) & 0xFFu);
                __builtin_amdgcn_s_setprio(1);
                #pragma unroll
                for (int i = 0; i < 4; ++i)
                    #pragma unroll
                    for (int j = 0; j < 4; ++j)
                        acc[i][j] = __builtin_amdgcn_mfma_f32_16x16x32_bf16(af[i], bfv[j], acc[i][j], 0, 0, 0);
                __builtin_amdgcn_s_setprio(0);
            }
        }
        float bj[4];
        #pragma unroll
        for (int j = 0; j < 4; ++j) bj[j] = bias[bn * 128 + wc + j * 16 + fm];
        int mb = (b << 10) + bmt * 128 + wr;
        #pragma unroll
        for (int i = 0; i < 4; ++i) {
            int m0 = mb + i * 16 + fq * 4;
            float s0 = SCALE[m0], s1 = SCALE[m0 + 1], s2 = SCALE[m0 + 2], s3 = SCALE[m0 + 3];
            #pragma unroll
            for (int j = 0; j < 4; ++j) {
                int c = bn * 128 + wc + j * 16 + fm;
                float* xo = XO + (size_t)m0 * 256 + c;
                xo[0]   = (acc[i][j][0] + bj[j]) * s0;
                xo[256] = (acc[i][j][1] + bj[j]) * s1;
                xo[512] = (acc[i][j][2] + bj[j]) * s2;
                xo[768] = (acc[i][j][3] + bj[j]) * s3;
            }
        }
    } else {
        int g = blockIdx.x - 256;
        int b = (g & 7) + ((g >> 9) << 3);         // batch pinned to XCD (g & 7)
        int grp = (g >> 3) & 63;
        __shared__ u64 sNMB[16];
        __shared__ u64 sRB[16][17];
        if (t < 16) sNMB[t] = NMBITS[b * 16 + t];
        sRB[t >> 4][t & 15] = ABITS[((size_t)((b << 10) + grp * 16 + (t >> 4))) * 16 + (t & 15)];
        __syncthreads();
        int c0 = t * 4;
        u64 wb = sNMB[c0 >> 6] >> (c0 & 63);
        float m0 = (wb & 1) ? 1.f : 0.f;
        float m1 = ((wb >> 1) & 1) ? 1.f : 0.f;
        float m2 = ((wb >> 2) & 1) ? 1.f : 0.f;
        float m3 = ((wb >> 3) & 1) ? 1.f : 0.f;
        #pragma unroll 1
        for (int r = 0; r < 16; ++r) {
            int rloc = grp * 16 + r;
            int nmRow = (int)((sNMB[rloc >> 6] >> (rloc & 63)) & 1ULL);
            float4* aor = (float4*)(AO + (size_t)((b << 10) + rloc) * 1024);
            if (nmRow) {
                unsigned rbits = (unsigned)(sRB[r][t >> 4] >> (4 * (t & 15))) & 0xFu;
                float4 o;
                o.x = (rbits & 1u) ? m0 : 0.f;
                o.y = (rbits & 2u) ? m1 : 0.f;
                o.z = (rbits & 4u) ? m2 : 0.f;
                o.w = (rbits & 8u) ? m3 : 0.f;
                aor[t] = o;
            } else {
                aor[t] = make_float4(0.f, 0.f, 0.f, 0.f);
            }
        }
    }
}

extern "C" void kernel_launch(void* const* d_in, const int* in_sizes, int n_in,
                              void* d_out, int out_size, void* d_ws, size_t ws_size,
                              hipStream_t stream) {
    const float* x      = (const float*)d_in[0];
    const float* adj    = (const float*)d_in[1];
    const int*   mask   = (const int*)d_in[2];
    const int*   nnodes = (const int*)d_in[3];
    const float* W      = (const float*)d_in[4];
    const float* bias   = (const float*)d_in[5];
    const float* pool   = (const float*)d_in[6];

    float* out = (float*)d_out;
    float* XO  = out;
    float* AO  = out + ADJ_OFF;
    float* NM  = out + MASK_OFF;
    float* NNo = out + NN_OFF;

    char* w = (char*)d_ws;
    u16*   XB     = (u16*)(w);                    //  8,388,608 B
    u16*   WT     = (u16*)(w + 8388608);          //    131,072
    u16*   XWBT   = (u16*)(w + 8519680);          //  8,388,608
    u64*   ABITS  = (u64*)(w + 16908288);         //  2,097,152
    float* Z      = (float*)(w + 19005440);       //     65,536
    float* Y      = (float*)(w + 19070976);       //     65,536
    float* SCALE  = (float*)(w + 19136512);       //     65,536
    u64*   NMBITS = (u64*)(w + 19202048);         //      2,048

    k1<<<272, 256, 0, stream>>>(x, W, pool, XB, WT, Z);
    k2<<<1280, 256, 0, stream>>>(XB, WT, adj, Z, XWBT, ABITS, Y);
    k3<<<Bsz, 1024, 0, stream>>>(Y, mask, nnodes, bias, pool, SCALE, NM, NNo, NMBITS);
    k4<<<1280, 256, 0, stream>>>(ABITS, XWBT, SCALE, bias, NMBITS, XO, AO);
}

// Round 8
// 200.333 us; speedup vs baseline: 1.0788x; 1.0151x over previous
//
#include <hip/hip_runtime.h>
#include <math.h>

// B=16, N=1024, C_IN=256, C_OUT=256, POOL_RATIO=0.5
#define Bsz 16
#define Nn  1024

// d_out layout (float32): x_out[16,1024,256], adj_out[16,1024,1024], new_mask[16,1024], new_n[16]
#define ADJ_OFF    (16*1024*256)
#define MASK_OFF   (ADJ_OFF + 16*1024*1024)
#define NN_OFF     (MASK_OFF + 16*1024)

typedef unsigned long long u64;
typedef unsigned short u16;
typedef short bf16x8 __attribute__((ext_vector_type(8)));
typedef float f32x4  __attribute__((ext_vector_type(4)));

static __device__ inline u16 f2bf(float f) {
    unsigned u = __float_as_uint(f);
    u += 0x7fffu + ((u >> 16) & 1u);
    return (u16)(u >> 16);
}

// spread 16 bits to every-4th position (bit q -> bit 4q)
static __device__ inline u64 spread4(u64 x) {
    x &= 0xFFFFULL;
    x = (x | (x << 24)) & 0x000000FF000000FFULL;
    x = (x | (x << 12)) & 0x000F000F000F000FULL;
    x = (x | (x << 6))  & 0x0303030303030303ULL;
    x = (x | (x << 3))  & 0x1111111111111111ULL;
    return x;
}

// expand 8 adjacency bits -> bf16x8 (bit -> 1.0bf16 = 0x3F80, exact same value as f2bf(1.0f))
static __device__ inline bf16x8 expand8(unsigned kb) {
    union { unsigned u[4]; bf16x8 v; } r;
    #pragma unroll
    for (int p = 0; p < 4; ++p) {
        unsigned lo = (kb >> (2 * p)) & 1u;
        unsigned hi = (kb >> (2 * p + 1)) & 1u;
        r.u[p] = (lo ? 0x3F80u : 0u) | (hi ? 0x3F800000u : 0u);
    }
    return r.v;
}

// =============== k1: x->bf16 + z = x.(W.pool) (blocks 0-255) | W^T bf16 (blocks 256-271) ===============
__global__ __launch_bounds__(256) void k1(const float* __restrict__ x,
                                          const float* __restrict__ W,
                                          const float* __restrict__ pool,
                                          u16* __restrict__ XB,
                                          u16* __restrict__ WT,
                                          float* __restrict__ Z) {
    int bid = blockIdx.x, t = threadIdx.x, lane = t & 63, wid = t >> 6;
    if (bid < 256) {
        __shared__ float sp[256];
        __shared__ float swp[256];
        sp[t] = pool[t];
        __syncthreads();
        float acc = 0.f;
        const float* wr = W + t * 256;
        for (int j = 0; j < 256; j += 4) {
            float4 w4 = *(const float4*)&wr[j];
            acc = fmaf(w4.x, sp[j], fmaf(w4.y, sp[j + 1],
                  fmaf(w4.z, sp[j + 2], fmaf(w4.w, sp[j + 3], acc))));
        }
        swp[t] = acc;
        __syncthreads();
        const float* w4p = &swp[lane * 4];
        float wx = w4p[0], wy = w4p[1], wz = w4p[2], ww = w4p[3];
        int base = bid * 64 + wid * 16;
        #pragma unroll 1
        for (int rb = 0; rb < 4; ++rb) {
            float4 v[4];
            #pragma unroll
            for (int k = 0; k < 4; ++k)
                v[k] = ((const float4*)(x + (size_t)(base + rb * 4 + k) * 256))[lane];
            #pragma unroll
            for (int k = 0; k < 4; ++k) {
                int row = base + rb * 4 + k;
                ushort4 o;
                o.x = f2bf(v[k].x); o.y = f2bf(v[k].y); o.z = f2bf(v[k].z); o.w = f2bf(v[k].w);
                ((ushort4*)(XB + (size_t)row * 256))[lane] = o;
                float a = fmaf(v[k].x, wx, fmaf(v[k].y, wy, fmaf(v[k].z, wz, v[k].w * ww)));
                for (int off = 32; off > 0; off >>= 1) a += __shfl_down(a, off, 64);
                if (lane == 0) Z[row] = a;
            }
        }
    } else {
        __shared__ float sT[64][65];
        int bt = bid - 256;
        int tr = (bt >> 2) * 64, tc = (bt & 3) * 64;
        #pragma unroll
        for (int p = 0; p < 4; ++p) {
            int r = p * 16 + (t >> 4), c = (t & 15) * 4;
            float4 w = *(const float4*)&W[(size_t)(tr + r) * 256 + tc + c];
            sT[r][c] = w.x; sT[r][c + 1] = w.y; sT[r][c + 2] = w.z; sT[r][c + 3] = w.w;
        }
        __syncthreads();
        #pragma unroll
        for (int p = 0; p < 2; ++p) {
            int nl = p * 32 + (t >> 3), kl = (t & 7) * 8;
            u16 tmp[8];
            #pragma unroll
            for (int j = 0; j < 8; ++j) tmp[j] = f2bf(sT[kl + j][nl]);
            *(int4*)&WT[(size_t)(tc + nl) * 256 + tr + kl] = *(const int4*)tmp;
        }
    }
}

// =============== k2: XWBT = (XB@WT^T)^T per batch (blocks 0-255, barrier-free direct-load GEMM)
//                 | adj->bitmask + y (blocks 256-1279) ===============
__global__ __launch_bounds__(256) void k2(const u16* __restrict__ XB,
                                          const u16* __restrict__ WT,
                                          const float* __restrict__ adj,
                                          const float* __restrict__ Z,
                                          u16* __restrict__ XWBT,
                                          u64* __restrict__ ABITS,
                                          float* __restrict__ Y) {
    int t = threadIdx.x, lane = t & 63, wid = t >> 6;
    if (blockIdx.x < 256) {
        __shared__ __align__(16) short sT[128][136];
        int idx = blockIdx.x;
        int b  = (idx & 7) + ((idx >> 7) << 3);    // batch pinned to XCD (idx & 7)
        int tl = (idx >> 3) & 15;                  // 16 tiles per batch
        int bm = (b << 3) + (tl >> 1);
        int bn = tl & 1;
        int wr = (wid >> 1) * 64, wc = (wid & 1) * 64;
        int fm = lane & 15, fq = lane >> 4;

        f32x4 acc[4][4];
        #pragma unroll
        for (int i = 0; i < 4; ++i)
            #pragma unroll
            for (int j = 0; j < 4; ++j)
                acc[i][j] = (f32x4){0.f, 0.f, 0.f, 0.f};

        const u16* baseA = XB + ((size_t)(bm * 128)) * 256;
        const u16* baseB = WT + ((size_t)(bn * 128)) * 256;

        #pragma unroll 1
        for (int kt = 0; kt < 4; ++kt) {
            #pragma unroll
            for (int ks = 0; ks < 64; ks += 32) {
                int ko = kt * 64 + ks + fq * 8;
                bf16x8 af[4], bfv[4];
                #pragma unroll
                for (int i = 0; i < 4; ++i)
                    af[i] = *(const bf16x8*)&baseA[(size_t)(wr + i * 16 + fm) * 256 + ko];
                #pragma unroll
                for (int j = 0; j < 4; ++j)
                    bfv[j] = *(const bf16x8*)&baseB[(size_t)(wc + j * 16 + fm) * 256 + ko];
                __builtin_amdgcn_s_setprio(1);
                #pragma unroll
                for (int i = 0; i < 4; ++i)
                    #pragma unroll
                    for (int j = 0; j < 4; ++j)
                        acc[i][j] = __builtin_amdgcn_mfma_f32_16x16x32_bf16(af[i], bfv[j], acc[i][j], 0, 0, 0);
                __builtin_amdgcn_s_setprio(0);
            }
        }
        // Transposed store via LDS so global writes are coalesced 16B chunks
        #pragma unroll
        for (int i = 0; i < 4; ++i) {
            int m = wr + i * 16 + fq * 4;
            #pragma unroll
            for (int j = 0; j < 4; ++j) {
                int c = wc + j * 16 + fm;
                #pragma unroll
                for (int r = 0; r < 4; ++r)
                    sT[c][m + r] = (short)f2bf(acc[i][j][r]);
            }
        }
        __syncthreads();
        u16* dst = XWBT + (size_t)b * 262144 + (size_t)(bn * 128) * 1024 + (bm & 7) * 128;
        int cl = t >> 4, mo = (t & 15) * 8;
        #pragma unroll
        for (int p = 0; p < 8; ++p) {
            int c = p * 16 + cl;
            *(int4*)&dst[(size_t)c * 1024 + mo] = *(const int4*)&sT[c][mo];
        }
    } else {
        int g = blockIdx.x - 256;
        int b = (g & 7) + ((g >> 9) << 3);
        int grp = (g >> 3) & 63;
        __shared__ float sZ[1024];
        ((float4*)sZ)[t] = ((const float4*)(Z + (b << 10)))[t];
        __syncthreads();
        const float* z0 = &sZ[lane * 4];
        #pragma unroll 1
        for (int rr = 0; rr < 4; ++rr) {
            int row = (b << 10) + grp * 16 + wid * 4 + rr;
            const float4* ar = (const float4*)(adj + (size_t)row * 1024);
            float4 v0 = ar[lane], v1 = ar[64 + lane], v2 = ar[128 + lane], v3 = ar[192 + lane];
            // ---- pack row into 1024-bit mask (canonical order: word w covers cols 64w..64w+63) ----
            u64 B00 = __ballot(v0.x != 0.f), B01 = __ballot(v0.y != 0.f);
            u64 B02 = __ballot(v0.z != 0.f), B03 = __ballot(v0.w != 0.f);
            u64 B10 = __ballot(v1.x != 0.f), B11 = __ballot(v1.y != 0.f);
            u64 B12 = __ballot(v1.z != 0.f), B13 = __ballot(v1.w != 0.f);
            u64 B20 = __ballot(v2.x != 0.f), B21 = __ballot(v2.y != 0.f);
            u64 B22 = __ballot(v2.z != 0.f), B23 = __ballot(v2.w != 0.f);
            u64 B30 = __ballot(v3.x != 0.f), B31 = __ballot(v3.y != 0.f);
            u64 B32 = __ballot(v3.z != 0.f), B33 = __ballot(v3.w != 0.f);
            u64 t0, t1, t2, t3;
            int c = (lane >> 2) & 3;
            if (c == 0)      { t0 = B00; t1 = B01; t2 = B02; t3 = B03; }
            else if (c == 1) { t0 = B10; t1 = B11; t2 = B12; t3 = B13; }
            else if (c == 2) { t0 = B20; t1 = B21; t2 = B22; t3 = B23; }
            else             { t0 = B30; t1 = B31; t2 = B32; t3 = B33; }
            int sh = (lane & 3) * 16;
            u64 wbits = spread4(t0 >> sh) | (spread4(t1 >> sh) << 1)
                      | (spread4(t2 >> sh) << 2) | (spread4(t3 >> sh) << 3);
            if (lane < 16) ABITS[(size_t)row * 16 + lane] = wbits;
            // ---- y = adj-row . z ----
            float a = v0.x * z0[0] + v0.y * z0[1] + v0.z * z0[2] + v0.w * z0[3];
            a += v1.x * z0[256] + v1.y * z0[257] + v1.z * z0[258] + v1.w * z0[259];
            a += v2.x * z0[512] + v2.y * z0[513] + v2.z * z0[514] + v2.w * z0[515];
            a += v3.x * z0[768] + v3.y * z0[769] + v3.z * z0[770] + v3.w * z0[771];
            for (int off = 32; off > 0; off >>= 1) a += __shfl_down(a, off, 64);
            if (lane == 0) Y[row] = a;
        }
    }
}

// =============== k3: radix-select pooling (replaces bitonic sort; same 16x1024 shape) ===============
// Stable-argsort removal == "remove masked i with ck_i < T", ck = (key32<<10)|idx (unique,
// encodes exact lex order), T = nrem-th smallest masked ck. 6 rounds x 7-bit radix select.
__global__ __launch_bounds__(1024) void k3(const float* __restrict__ Y,
                                           const int* __restrict__ maskIn,
                                           const int* __restrict__ nNodes,
                                           const float* __restrict__ bias,
                                           const float* __restrict__ pool,
                                           float* __restrict__ SCALE,
                                           float* __restrict__ NM,
                                           float* __restrict__ newN,
                                           u64* __restrict__ NMBITS) {
    __shared__ int sHist[128];
    __shared__ int sScan[2];
    __shared__ int wsumM[16];
    __shared__ float redb[4], redq[4];
    __shared__ int sSel, sTgt;

    int b = blockIdx.x, t = threadIdx.x, lane = t & 63, wid = t >> 6;
    int base = b << 10;

    if (t < 256) {
        float pv = pool[t];
        float bv = bias[t] * pv;
        float qv = pv * pv;
        for (int off = 32; off > 0; off >>= 1) {
            bv += __shfl_down(bv, off, 64);
            qv += __shfl_down(qv, off, 64);
        }
        if (lane == 0) { redb[wid] = bv; redq[wid] = qv; }
    }

    float ky = Y[base + t];
    unsigned u = __float_as_uint(ky);
    u = (u & 0x80000000u) ? ~u : (u | 0x80000000u);
    int mval = maskIn[base + t];
    u64 ck = ((u64)u << 10) | (unsigned)t;           // 42-bit unique lex key

    int ms = mval;
    for (int off = 32; off > 0; off >>= 1) ms += __shfl_down(ms, off, 64);
    if (lane == 0) wsumM[wid] = ms;
    __syncthreads();

    float sBP  = redb[0] + redb[1] + redb[2] + redb[3];
    float sINV = 1.0f / sqrtf(redq[0] + redq[1] + redq[2] + redq[3]);
    int mtotal = 0;
    #pragma unroll
    for (int w = 0; w < 16; ++w) mtotal += wsumM[w];

    int nn = nNodes[b];
    int nrem = (int)((float)nn * 0.5f);

    u64 T;
    if (nrem >= mtotal) {
        T = ~0ULL;                                   // remove all masked
    } else {
        u64 prefix = 0;
        int target = nrem;
        for (int r = 0; r < 6; ++r) {
            int shift = 35 - 7 * r;
            if (t < 128) sHist[t] = 0;
            __syncthreads();
            bool active = (mval != 0) && ((ck >> (shift + 7)) == prefix);
            if (active) atomicAdd(&sHist[(int)((ck >> shift) & 127)], 1);
            __syncthreads();
            int x = 0, v = 0;
            if (t < 128) {
                v = sHist[t];
                x = v;
                for (int o = 1; o < 64; o <<= 1) { int n = __shfl_up(x, o, 64); if (lane >= o) x += n; }
                if (lane == 63) sScan[t >> 6] = x;   // per-wave totals
            }
            __syncthreads();
            if (t < 128) {
                int incl = x + ((t >= 64) ? sScan[0] : 0);
                int excl = incl - v;
                if (excl <= target && target < incl) { sSel = t; sTgt = target - excl; }
            }
            __syncthreads();
            prefix = (prefix << 7) | (unsigned)sSel;
            target = sTgt;
        }
        T = prefix;                                  // the selected ck itself
    }

    int nm = (mval == 1 && ck < T) ? 0 : mval;
    NM[base + t] = (float)nm;                        // coalesced (was scatter by sorted idx)
    u64 bmask = __ballot(nm != 0);
    if (lane == 0) NMBITS[b * 16 + wid] = bmask;
    SCALE[base + t] = nm ? tanhf((ky + sBP) * sINV) : 0.0f;
    if (t == 0) newN[b] = (float)(nn - nrem);
}

// =============== k4: H=Abits@XWBT^T + x_out epilogue (blocks 0-255, barrier-free direct-load GEMM)
//                 | AO dense write (blocks 256-1279) ===============
__global__ __launch_bounds__(256) void k4(const u64* __restrict__ ABITS,
                                          const u16* __restrict__ XWBT,
                                          const float* __restrict__ SCALE,
                                          const float* __restrict__ bias,
                                          const u64* __restrict__ NMBITS,
                                          float* __restrict__ XO,
                                          float* __restrict__ AO) {
    int t = threadIdx.x, lane = t & 63, wid = t >> 6;
    if (blockIdx.x < 256) {
        __shared__ u64 sBitsA[128][18];   // 18,432 B, staged once
        int idx = blockIdx.x;
        int b   = (idx & 7) + ((idx >> 7) << 3);   // batch pinned to XCD (idx & 7)
        int tl  = (idx >> 3) & 15;
        int bmt = tl >> 1, bn = tl & 1;
        int wr = (wid >> 1) * 64, wc = (wid & 1) * 64;
        int fm = lane & 15, fq = lane >> 4;

        {
            int r = t >> 1, hq = (t & 1) * 8;
            const u64* src = ABITS + ((size_t)(b * 1024 + bmt * 128 + r)) * 16 + hq;
            #pragma unroll
            for (int q = 0; q < 8; q += 2) {
                ulonglong2 v = *(const ulonglong2*)&src[q];
                sBitsA[r][hq + q] = v.x;
                sBitsA[r][hq + q + 1] = v.y;
            }
        }

        f32x4 acc[4][4];
        #pragma unroll
        for (int i = 0; i < 4; ++i)
            #pragma unroll
            for (int j = 0; j < 4; ++j)
                acc[i][j] = (f32x4){0.f, 0.f, 0.f, 0.f};

        const u16* baseB = XWBT + (size_t)b * 262144 + (size_t)(bn * 128) * 1024;
        __syncthreads();   // sBitsA ready; no further barriers

        #pragma unroll 1
        for (int kt = 0; kt < 16; ++kt) {
            u64 rb[4];
            #pragma unroll
            for (int i = 0; i < 4; ++i)
                rb[i] = sBitsA[wr + i * 16 + fm][kt];
            #pragma unroll
            for (int ks = 0; ks < 64; ks += 32) {
                bf16x8 af[4], bfv[4];
                #pragma unroll
                for (int j = 0; j < 4; ++j)
                    bfv[j] = *(const bf16x8*)&baseB[(size_t)(wc + j * 16 + fm) * 1024 + kt * 64 + ks + fq * 8];
                #pragma unroll
                for (int i = 0; i < 4; ++i)
                    af[i] = expand8((unsigned)(rb[i] >> (ks + fq * 8)) & 0xFFu);
                __builtin_amdgcn_s_setprio(1);
                #pragma unroll
                for (int i = 0; i < 4; ++i)
                    #pragma unroll
                    for (int j = 0; j < 4; ++j)
                        acc[i][j] = __builtin_amdgcn_mfma_f32_16x16x32_bf16(af[i], bfv[j], acc[i][j], 0, 0, 0);
                __builtin_amdgcn_s_setprio(0);
            }
        }
        float bj[4];
        #pragma unroll
        for (int j = 0; j < 4; ++j) bj[j] = bias[bn * 128 + wc + j * 16 + fm];
        int mb = (b << 10) + bmt * 128 + wr;
        #pragma unroll
        for (int i = 0; i < 4; ++i) {
            int m0 = mb + i * 16 + fq * 4;
            float s0 = SCALE[m0], s1 = SCALE[m0 + 1], s2 = SCALE[m0 + 2], s3 = SCALE[m0 + 3];
            #pragma unroll
            for (int j = 0; j < 4; ++j) {
                int c = bn * 128 + wc + j * 16 + fm;
                float* xo = XO + (size_t)m0 * 256 + c;
                xo[0]   = (acc[i][j][0] + bj[j]) * s0;
                xo[256] = (acc[i][j][1] + bj[j]) * s1;
                xo[512] = (acc[i][j][2] + bj[j]) * s2;
                xo[768] = (acc[i][j][3] + bj[j]) * s3;
            }
        }
    } else {
        int g = blockIdx.x - 256;
        int b = (g & 7) + ((g >> 9) << 3);         // batch pinned to XCD (g & 7)
        int grp = (g >> 3) & 63;
        __shared__ u64 sNMB[16];
        __shared__ u64 sRB[16][17];
        if (t < 16) sNMB[t] = NMBITS[b * 16 + t];
        sRB[t >> 4][t & 15] = ABITS[((size_t)((b << 10) + grp * 16 + (t >> 4))) * 16 + (t & 15)];
        __syncthreads();
        int c0 = t * 4;
        u64 wb = sNMB[c0 >> 6] >> (c0 & 63);
        float m0 = (wb & 1) ? 1.f : 0.f;
        float m1 = ((wb >> 1) & 1) ? 1.f : 0.f;
        float m2 = ((wb >> 2) & 1) ? 1.f : 0.f;
        float m3 = ((wb >> 3) & 1) ? 1.f : 0.f;
        #pragma unroll 1
        for (int r = 0; r < 16; ++r) {
            int rloc = grp * 16 + r;
            int nmRow = (int)((sNMB[rloc >> 6] >> (rloc & 63)) & 1ULL);
            float4* aor = (float4*)(AO + (size_t)((b << 10) + rloc) * 1024);
            if (nmRow) {
                unsigned rbits = (unsigned)(sRB[r][t >> 4] >> (4 * (t & 15))) & 0xFu;
                float4 o;
                o.x = (rbits & 1u) ? m0 : 0.f;
                o.y = (rbits & 2u) ? m1 : 0.f;
                o.z = (rbits & 4u) ? m2 : 0.f;
                o.w = (rbits & 8u) ? m3 : 0.f;
                aor[t] = o;
            } else {
                aor[t] = make_float4(0.f, 0.f, 0.f, 0.f);
            }
        }
    }
}

extern "C" void kernel_launch(void* const* d_in, const int* in_sizes, int n_in,
                              void* d_out, int out_size, void* d_ws, size_t ws_size,
                              hipStream_t stream) {
    const float* x      = (const float*)d_in[0];
    const float* adj    = (const float*)d_in[1];
    const int*   mask   = (const int*)d_in[2];
    const int*   nnodes = (const int*)d_in[3];
    const float* W      = (const float*)d_in[4];
    const float* bias   = (const float*)d_in[5];
    const float* pool   = (const float*)d_in[6];

    float* out = (float*)d_out;
    float* XO  = out;
    float* AO  = out + ADJ_OFF;
    float* NM  = out + MASK_OFF;
    float* NNo = out + NN_OFF;

    char* w = (char*)d_ws;
    u16*   XB     = (u16*)(w);                    //  8,388,608 B
    u16*   WT     = (u16*)(w + 8388608);          //    131,072
    u16*   XWBT   = (u16*)(w + 8519680);          //  8,388,608
    u64*   ABITS  = (u64*)(w + 16908288);         //  2,097,152
    float* Z      = (float*)(w + 19005440);       //     65,536
    float* Y      = (float*)(w + 19070976);       //     65,536
    float* SCALE  = (float*)(w + 19136512);       //     65,536
    u64*   NMBITS = (u64*)(w + 19202048);         //      2,048

    k1<<<272, 256, 0, stream>>>(x, W, pool, XB, WT, Z);
    k2<<<1280, 256, 0, stream>>>(XB, WT, adj, Z, XWBT, ABITS, Y);
    k3<<<Bsz, 1024, 0, stream>>>(Y, mask, nnodes, bias, pool, SCALE, NM, NNo, NMBITS);
    k4<<<1280, 256, 0, stream>>>(ABITS, XWBT, SCALE, bias, NMBITS, XO, AO);
}